// Round 1
// 437.660 us; speedup vs baseline: 1.2397x; 1.2397x over previous
//
#include <hip/hip_runtime.h>
#include <hip/hip_bf16.h>

#define M_DIM 8192
#define N_DIM 4096
#define K_DIM 4096

typedef __attribute__((ext_vector_type(4))) int int4v;

// ---------------------------------------------------------------------------
// pack 4 rounded/clamped floats (as ints) into one int32 (little-endian bytes)
// ---------------------------------------------------------------------------
__device__ __forceinline__ int quant4(float4 v, float rs) {
    float r0 = rintf(v.x * rs), r1 = rintf(v.y * rs);
    float r2 = rintf(v.z * rs), r3 = rintf(v.w * rs);
    int i0 = (int)fminf(127.0f, fmaxf(-128.0f, r0));
    int i1 = (int)fminf(127.0f, fmaxf(-128.0f, r1));
    int i2 = (int)fminf(127.0f, fmaxf(-128.0f, r2));
    int i3 = (int)fminf(127.0f, fmaxf(-128.0f, r3));
    return (i0 & 255) | ((i1 & 255) << 8) | ((i2 & 255) << 16) | (i3 << 24);
}

__device__ __forceinline__ int pack4i(int4 v) {
    return (v.x & 255) | ((v.y & 255) << 8) | ((v.z & 255) << 16) | (v.w << 24);
}

// ---------------------------------------------------------------------------
// P1: blocks [0,1024): ternary int32 weight -> int8 (independent of absmax)
//     blocks [1024,3072): absmax of x -> amax (uint bits, |x| >= 0)
// ---------------------------------------------------------------------------
#define WCVT_BLOCKS 1024
#define ABS_BLOCKS 2048
__global__ void prep1_kernel(const float4* __restrict__ x,
                             const int4* __restrict__ w,
                             int* __restrict__ wq,
                             unsigned* __restrict__ amax) {
    if (blockIdx.x < WCVT_BLOCKS) {
        const int t = WCVT_BLOCKS * 256;
        const int n = (N_DIM * K_DIM) / 4;  // int4 count
        for (int i = blockIdx.x * 256 + threadIdx.x; i < n; i += 4 * t) {
            int4 a = w[i], b = w[i + t], c = w[i + 2 * t], d = w[i + 3 * t];
            wq[i] = pack4i(a);
            wq[i + t] = pack4i(b);
            wq[i + 2 * t] = pack4i(c);
            wq[i + 3 * t] = pack4i(d);
        }
    } else {
        const int t = ABS_BLOCKS * 256;
        const int n = (M_DIM * K_DIM) / 4;  // float4 count
        float m = 0.0f;
        for (int i = (blockIdx.x - WCVT_BLOCKS) * 256 + threadIdx.x; i < n;
             i += 4 * t) {
            float4 a = x[i], b = x[i + t], c = x[i + 2 * t], d = x[i + 3 * t];
            float ma = fmaxf(fmaxf(fabsf(a.x), fabsf(a.y)), fmaxf(fabsf(a.z), fabsf(a.w)));
            float mb = fmaxf(fmaxf(fabsf(b.x), fabsf(b.y)), fmaxf(fabsf(b.z), fabsf(b.w)));
            float mc = fmaxf(fmaxf(fabsf(c.x), fabsf(c.y)), fmaxf(fabsf(c.z), fabsf(c.w)));
            float md = fmaxf(fmaxf(fabsf(d.x), fabsf(d.y)), fmaxf(fabsf(d.z), fabsf(d.w)));
            m = fmaxf(m, fmaxf(fmaxf(ma, mb), fmaxf(mc, md)));
        }
        #pragma unroll
        for (int off = 32; off > 0; off >>= 1)
            m = fmaxf(m, __shfl_down(m, off, 64));
        __shared__ float sm[4];
        if ((threadIdx.x & 63) == 0) sm[threadIdx.x >> 6] = m;
        __syncthreads();
        if (threadIdx.x == 0) {
            float b = fmaxf(fmaxf(sm[0], sm[1]), fmaxf(sm[2], sm[3]));
            atomicMax(amax, __float_as_uint(b));
        }
    }
}

// ---------------------------------------------------------------------------
// P2: quantize x -> int8 (rintf = round-half-even = jnp.round, then clamp)
// ---------------------------------------------------------------------------
#define QUANT_BLOCKS 2048
__global__ void quant_kernel(const float4* __restrict__ x, int* __restrict__ q,
                             const unsigned* __restrict__ amax_u) {
    float amax = __uint_as_float(*amax_u);
    float scale = amax * (1.0f / 127.0f);
    if (scale == 0.0f) scale = 1.0f;
    const float rs = 1.0f / scale;
    const int t = QUANT_BLOCKS * 256;
    const int n = (M_DIM * K_DIM) / 4;  // float4 count (== int8x4 outputs)
    for (int i = blockIdx.x * 256 + threadIdx.x; i < n; i += 4 * t) {
        float4 a = x[i], b = x[i + t], c = x[i + 2 * t], d = x[i + 3 * t];
        q[i] = quant4(a, rs);
        q[i + t] = quant4(b, rs);
        q[i + 2 * t] = quant4(c, rs);
        q[i + 3 * t] = quant4(d, rs);
    }
}

// ---------------------------------------------------------------------------
// GEMM: i8, B-transposed. A:[M,K] i8, B:[N,K] i8, C:[M,N] f32.
//
// 256x256 tile, BK=64, 8 waves (2M x 4N), mfma_i32_16x16x64_i8.
// Phase-scheduled K-loop (ported from the verified 256^2 8-phase bf16
// template): 4 LDS buffers (4 x 32 KiB = 128 KiB), staging 3 K-tiles
// ahead via global_load_lds, counted s_waitcnt vmcnt(8) once per K-tile
// (never 0 in the main loop), raw s_barrier pairs around 16-MFMA
// clusters wrapped in s_setprio(1).
//
// LDS layout = gload-lds linear write order == fragment read order
// (lane*16B within 16-row x 64B segments) -> conflict-free ds_read_b128
// with NO swizzle (bank-conflict counter was 0 on this layout).
// ---------------------------------------------------------------------------
__device__ __forceinline__ void gload16(const char* g, char* l) {
    __builtin_amdgcn_global_load_lds(
        (const __attribute__((address_space(1))) unsigned int*)g,
        (__attribute__((address_space(3))) unsigned int*)l,
        16, 0, 0);
}

#define FENCE() asm volatile("" ::: "memory")
#define BAR()                                \
    do {                                     \
        FENCE();                             \
        __builtin_amdgcn_s_barrier();        \
        FENCE();                             \
    } while (0)

__global__ __launch_bounds__(512, 2) void gemm_i8(
    const char* __restrict__ A,
    const char* __restrict__ B,
    float* __restrict__ C,
    const float* __restrict__ bias,
    const float* __restrict__ wscale,
    const unsigned* __restrict__ amax_u) {
    // 4 buffers x (A 16KB + B 16KB) = 128 KiB
    __shared__ __align__(16) char L[4][32768];

    // ---- XCD-aware tile swizzle: 512 wgs, 8 XCDs, 8x8-tile patches ----
    // 32 M-tiles x 16 N-tiles. 8 patches: 4 along M, 2 along N; serpentine.
    const int f = blockIdx.x;
    const int xcd = f & 7;
    const int slot = f >> 3;      // 0..63
    const int sm = slot >> 3;     // 0..7
    int sn = slot & 7;
    if (sm & 1) sn = 7 - sn;
    const int mBase = ((xcd >> 1) * 8 + sm) * 256;
    const int nBase = ((xcd & 1) * 8 + sn) * 256;

    const int t = threadIdx.x;
    const int w = t >> 6;   // wave 0..7
    const int l = t & 63;
    const int lm = l & 15;
    const int lq = l >> 4;
    const int wm = w >> 2;  // 0..1  (M half: 128 rows)
    const int wn = w & 3;   // 0..3  (N quarter: 64 cols)

    // Fixed staging role per thread: stage slot p handles segment idx = p*8+w.
    // Segments 0..15 = A (16 rows x 64B each), 16..31 = B.
    const char* gp[4];
    int lo[4];
    #pragma unroll
    for (int p = 0; p < 4; ++p) {
        const int idx = p * 8 + w;
        if (idx < 16) {
            gp[p] = A + (size_t)(mBase + idx * 16 + lm) * K_DIM + lq * 16;
            lo[p] = idx * 1024;
        } else {
            gp[p] = B + (size_t)(nBase + (idx - 16) * 16 + lm) * K_DIM + lq * 16;
            lo[p] = 16384 + (idx - 16) * 1024;
        }
    }

    #define STG(tt, p) gload16(gp[p] + (size_t)(tt) * 64, &L[(tt) & 3][0] + lo[p])

    // ---- prologue: stage K-tiles 0,1,2 (12 gload16/thread) ----
    #pragma unroll
    for (int tt = 0; tt < 3; ++tt) {
        STG(tt, 0);
        STG(tt, 1);
        STG(tt, 2);
        STG(tt, 3);
    }

    int4v acc[8][4];
    #pragma unroll
    for (int r = 0; r < 8; ++r)
        #pragma unroll
        for (int c = 0; c < 4; ++c)
            acc[r][c] = (int4v){0, 0, 0, 0};

    asm volatile("s_waitcnt vmcnt(8)" ::: "memory");  // tile 0 landed
    BAR();

    // One K-tile: 2 phases x {ds_read frags; issue 2 stage loads; barrier;
    // setprio(1); 16 MFMA; setprio(0); barrier}. vmcnt(N) only in phase 1.
    #define KTILE(u, DO_STAGE, VMSTR)                                           \
    do {                                                                        \
        const char* lb = &L[(u) & 3][0];                                        \
        const char* aB = lb + wm * 8192 + l * 16;                               \
        const char* bB = lb + 16384 + wn * 4096 + l * 16;                       \
        int4v af[4], bf[4];                                                     \
        /* ---- phase 0: rows 0..3 of the wave's 8 M-frags ---- */              \
        _Pragma("unroll")                                                       \
        for (int r = 0; r < 4; ++r) af[r] = *(const int4v*)(aB + r * 1024);     \
        _Pragma("unroll")                                                       \
        for (int c = 0; c < 4; ++c) bf[c] = *(const int4v*)(bB + c * 1024);     \
        if (DO_STAGE) { STG((u) + 3, 0); STG((u) + 3, 1); }                     \
        BAR();                                                                  \
        __builtin_amdgcn_s_setprio(1);                                          \
        _Pragma("unroll")                                                       \
        for (int r = 0; r < 4; ++r)                                             \
            _Pragma("unroll")                                                   \
            for (int c = 0; c < 4; ++c)                                         \
                acc[r][c] = __builtin_amdgcn_mfma_i32_16x16x64_i8(              \
                    af[r], bf[c], acc[r][c], 0, 0, 0);                          \
        __builtin_amdgcn_s_setprio(0);                                          \
        BAR();                                                                  \
        /* ---- phase 1: rows 4..7 ---- */                                      \
        _Pragma("unroll")                                                       \
        for (int r = 0; r < 4; ++r)                                             \
            af[r] = *(const int4v*)(aB + (4 + r) * 1024);                       \
        if (DO_STAGE) { STG((u) + 3, 2); STG((u) + 3, 3); }                     \
        asm volatile("s_waitcnt " VMSTR ::: "memory");                          \
        BAR();                                                                  \
        __builtin_amdgcn_s_setprio(1);                                          \
        _Pragma("unroll")                                                       \
        for (int r = 0; r < 4; ++r)                                             \
            _Pragma("unroll")                                                   \
            for (int c = 0; c < 4; ++c)                                         \
                acc[4 + r][c] = __builtin_amdgcn_mfma_i32_16x16x64_i8(          \
                    af[r], bf[c], acc[4 + r][c], 0, 0, 0);                      \
        __builtin_amdgcn_s_setprio(0);                                          \
        BAR();                                                                  \
    } while (0)

    // Main loop: stage tile u+3; vmcnt(8) = loads for {u+2,u+3} may remain
    // in flight across the tile boundary (tile u+1 guaranteed landed).
    #pragma unroll 1
    for (int u = 0; u < 61; ++u) {
        KTILE(u, true, "vmcnt(8)");
    }
    // Drain epilogue: no more stages; counted waits shrink 8 -> 4 -> 0.
    KTILE(61, false, "vmcnt(4)");
    KTILE(62, false, "vmcnt(0)");
    KTILE(63, false, "vmcnt(0)");

    #undef KTILE
    #undef STG

    // ---- epilogue: scale + bias, same verified C/D mapping ----
    float amax = __uint_as_float(*amax_u);
    float scale = amax * (1.0f / 127.0f);
    if (scale == 0.0f) scale = 1.0f;
    const float s = wscale[0] * scale;

    #pragma unroll
    for (int ct = 0; ct < 4; ++ct) {
        const int col = nBase + wn * 64 + ct * 16 + lm;
        const float bb = bias[col];
        #pragma unroll
        for (int rt = 0; rt < 8; ++rt) {
            const int row0 = mBase + wm * 128 + rt * 16 + lq * 4;
            #pragma unroll
            for (int r = 0; r < 4; ++r) {
                C[(size_t)(row0 + r) * N_DIM + col] = (float)acc[rt][ct][r] * s + bb;
            }
        }
    }
}

// ---------------------------------------------------------------------------
extern "C" void kernel_launch(void* const* d_in, const int* in_sizes, int n_in,
                              void* d_out, int out_size, void* d_ws, size_t ws_size,
                              hipStream_t stream) {
    const float* x      = (const float*)d_in[0];   // [8192,4096] fp32
    const int* weight   = (const int*)d_in[1];     // [4096,4096] int32 ternary
    const float* wscale = (const float*)d_in[2];   // scalar
    const float* bias   = (const float*)d_in[3];   // [4096]
    float* out          = (float*)d_out;           // [8192,4096] fp32

    unsigned char* ws = (unsigned char*)d_ws;
    unsigned* amax = (unsigned*)ws;                             // 4 B
    char* Aq = (char*)(ws + 256);                               // M*K i8 = 32 MB
    char* Wb = (char*)(ws + 256 + (size_t)M_DIM * K_DIM);       // N*K i8 = 16 MB

    hipMemsetAsync(amax, 0, sizeof(unsigned), stream);

    prep1_kernel<<<WCVT_BLOCKS + ABS_BLOCKS, 256, 0, stream>>>(
        (const float4*)x, (const int4*)weight, (int*)Wb, amax);
    quant_kernel<<<QUANT_BLOCKS, 256, 0, stream>>>((const float4*)x, (int*)Aq, amax);

    gemm_i8<<<512, 512, 0, stream>>>(Aq, Wb, out, bias, wscale, amax);
}